// Round 1
// baseline (772.592 us; speedup 1.0000x reference)
//
#include <hip/hip_runtime.h>
#include <stdint.h>

#define NN 2048
#define LL 21
#define CAP 200

typedef unsigned long long u64;
typedef unsigned int u32;

__device__ __forceinline__ u64 shfl_u64(u64 v, int lane) {
    int lo = (int)(u32)(v & 0xFFFFFFFFull);
    int hi = (int)(u32)(v >> 32);
    lo = __shfl(lo, lane);
    hi = __shfl(hi, lane);
    return ((u64)(u32)hi << 32) | (u32)lo;
}

__device__ __forceinline__ u64 shfl_xor_u64(u64 v, int mask) {
    int lo = (int)(u32)(v & 0xFFFFFFFFull);
    int hi = (int)(u32)(v >> 32);
    lo = __shfl_xor(lo, mask);
    hi = __shfl_xor(hi, mask);
    return ((u64)(u32)hi << 32) | (u32)lo;
}

__device__ __forceinline__ float4 clip01(float4 b) {
    b.x = fminf(fmaxf(b.x, 0.0f), 1.0f);
    b.y = fminf(fmaxf(b.y, 0.0f), 1.0f);
    b.z = fminf(fmaxf(b.z, 0.0f), 1.0f);
    b.w = fminf(fmaxf(b.w, 0.0f), 1.0f);
    return b;
}

// decode with VARIANCES=(0.1,0.1,0.2,0.2); match np op order (no FMA contraction),
// exp via double for correct rounding to f32.
__device__ __forceinline__ float4 decode_box(const float4 roi, const float4 dd) {
#pragma clang fp contract(off)
    float h  = roi.z - roi.x;
    float w  = roi.w - roi.y;
    float cy = roi.x + 0.5f * h;
    float cx = roi.y + 0.5f * w;
    float d0 = dd.x * 0.1f;
    float d1 = dd.y * 0.1f;
    float d2 = dd.z * 0.2f;
    float d3 = dd.w * 0.2f;
    float nh = (float)exp((double)d2) * h;
    float nw = (float)exp((double)d3) * w;
    float ncy = d0 * h + cy;
    float ncx = d1 * w + cx;
    return make_float4(ncy - 0.5f * nh, ncx - 0.5f * nw, ncy + 0.5f * nh, ncx + 0.5f * nw);
}

// exact replication of reference IoU>0.5 decision (division kept, op order kept)
__device__ __forceinline__ bool iou_gt(const float4 a, const float4 b) {
#pragma clang fp contract(off)
    float areaA = (a.z - a.x) * (a.w - a.y);
    float areaB = (b.z - b.x) * (b.w - b.y);
    float ih = fminf(a.z, b.z) - fmaxf(a.x, b.x);
    ih = fmaxf(ih, 0.0f);
    float iw = fminf(a.w, b.w) - fmaxf(a.y, b.y);
    iw = fmaxf(iw, 0.0f);
    float inter = ih * iw;
    float denom = ((areaA + areaB) - inter) + 1e-9f;
    return (inter / denom) > 0.5f;
}

// One block per class: scores (argmax mask) -> bitonic sort -> filtered greedy NMS
// -> cap 200 -> emit global candidates + per-class fallback top-1.
__global__ __launch_bounds__(256) void per_class_kernel(
    const float* __restrict__ roi,      // (N,4)
    const float* __restrict__ deltas,   // (N, L*4)
    const float* __restrict__ probs,    // (N, L)
    u64* __restrict__ cand_key,         // (L*CAP)
    float4* __restrict__ cand_box,      // (L*CAP)
    u64* __restrict__ fb_key,           // (L)
    float4* __restrict__ fb_box)        // (L)
{
    const int cls = blockIdx.x;
    const int t = threadIdx.x;

    __shared__ u64 skey[NN];              // 16 KB sort keys: score_bits<<32 | ~anchor
    __shared__ float4 sbox[NN];           // 32 KB sorted decoded boxes (filtered prefix)
    __shared__ u64 kw[NN / 64];           // keep bitmask
    __shared__ u64 sup[64];               // intra-chunk suppression rows
    __shared__ unsigned char extq[4][64]; // external suppression per quarter
    __shared__ int sM;
    __shared__ int pfx[NN / 64];

    // zero our candidate slots (ws is poisoned each call)
    for (int s = t; s < CAP; s += 256) cand_key[cls * CAP + s] = 0ull;

    // 1. scores: zero whole row when argmax class == 0 (background)
    for (int a = t; a < NN; a += 256) {
        const float* p = probs + a * LL;
        float best = p[0];
        int bi = 0;
        float mysc = p[cls];
        for (int j = 1; j < LL; ++j) {
            float v = p[j];
            if (v > best) { best = v; bi = j; }
        }
        float sc = (bi != 0) ? mysc : 0.0f;
        // descending by score, tie: ascending anchor index (stable argsort of -scores)
        skey[a] = ((u64)__float_as_uint(sc) << 32) | (u32)(~(u32)a);
    }
    __syncthreads();

    // 2. bitonic sort, descending (unique keys)
    for (int k = 2; k <= NN; k <<= 1) {
        for (int j = k >> 1; j > 0; j >>= 1) {
            for (int i = t; i < NN; i += 256) {
                int ixj = i ^ j;
                if (ixj > i) {
                    u64 a = skey[i], b = skey[ixj];
                    bool dsc = ((i & k) == 0);
                    if (dsc ? (a < b) : (a > b)) { skey[i] = b; skey[ixj] = a; }
                }
            }
            __syncthreads();
        }
    }

    // 3. M = count(score > 0.5): prefix boundary in sorted order
    if (t == 0) sM = 0;
    __syncthreads();
    const u64 THRKEY = ((u64)0x3F000000u << 32) | 0xFFFFFFFFull; // score must be > 0.5 strictly
    for (int i = t; i < NN; i += 256) {
        bool in = skey[i] > THRKEY;
        bool nin = (i + 1 < NN) ? (skey[i + 1] > THRKEY) : false;
        if (in && !nin) sM = i + 1;
    }
    __syncthreads();
    const int M = sM;

    // 4. decode boxes for filtered prefix; write per-class fallback (rank-0, always kept)
    for (int r = t; r < M; r += 256) {
        u32 a = ~(u32)(skey[r] & 0xFFFFFFFFull);
        float4 rb = *(const float4*)(roi + a * 4);
        float4 dd = *(const float4*)(deltas + a * (LL * 4) + cls * 4);
        sbox[r] = decode_box(rb, dd);
    }
    if (t == 0) {
        u32 a0 = ~(u32)(skey[0] & 0xFFFFFFFFull);
        float4 rb = *(const float4*)(roi + a0 * 4);
        float4 dd = *(const float4*)(deltas + a0 * (LL * 4) + cls * 4);
        fb_box[cls] = decode_box(rb, dd);
        // tie-break across classes by flat index c*N (smaller class wins)
        fb_key[cls] = (skey[0] & 0xFFFFFFFF00000000ull) | (u32)(~(u32)(cls * NN));
    }
    if (t < NN / 64) kw[t] = 0ull;
    __syncthreads();

    // 5. chunked exact greedy NMS over filtered prefix
    const int NC = (M + 63) / 64;
    for (int c0 = 0; c0 < NC; ++c0) {
        const int base = c0 * 64;
        const int nb = min(64, M - base);
        // 5a. intra-chunk pair bits (wave 0; lane r1 builds row of r2>r1 overlaps)
        if (t < 64) {
            u64 row = 0ull;
            if (t < nb) {
                float4 bi = sbox[base + t];
                for (int r2 = t + 1; r2 < nb; ++r2)
                    if (iou_gt(bi, sbox[base + r2])) row |= (1ull << r2);
            }
            sup[t] = row;
        }
        // 5b. suppression by earlier KEPT boxes (256 threads: 64 boxes x 4 quarters)
        {
            const int r = t & 63;
            const int q = t >> 6;
            bool f = false;
            if (r < nb && base > 0) {
                float4 bm = sbox[base + r];
                const int per = base >> 2;
                const int e0 = q * per, e1 = e0 + per;
                for (int e = e0; e < e1; ++e) {
                    if ((kw[e >> 6] >> (e & 63)) & 1ull) {
                        if (iou_gt(sbox[e], bm)) { f = true; break; }
                    }
                }
            }
            extq[q][r] = f ? 1 : 0;
        }
        __syncthreads();
        // 5c. wave-synchronous sequential resolve within chunk
        if (t < 64) {
            bool extf = (t < nb) ? ((extq[0][t] | extq[1][t] | extq[2][t] | extq[3][t]) != 0) : true;
            u64 removed = __ballot(extf);
            u64 myrow = sup[t];
            u64 keepbits = 0ull;
            for (int r = 0; r < nb; ++r) {
                u64 rr = shfl_u64(myrow, r);  // all lanes execute
                if (!((removed >> r) & 1ull)) {
                    keepbits |= (1ull << r);
                    removed |= rr;
                }
            }
            if (t == 0) kw[c0] = keepbits;
        }
        __syncthreads();
    }

    // 6. kept-rank prefix and candidate emission (cap 200 per class)
    if (t == 0) {
        int run = 0;
        for (int w = 0; w < NN / 64; ++w) { pfx[w] = run; run += __popcll(kw[w]); }
    }
    __syncthreads();
    for (int r = t; r < M; r += 256) {
        u64 word = kw[r >> 6];
        if ((word >> (r & 63)) & 1ull) {
            int krank = pfx[r >> 6] + __popcll(word & ((1ull << (r & 63)) - 1ull));
            if (krank < CAP) {
                int slot = cls * CAP + krank;
                // low bits ~slot: slot order is isomorphic to flat (c*2048+rank) order,
                // reproducing lax.top_k tie-break (lower flat index first)
                cand_key[slot] = (skey[r] & 0xFFFFFFFF00000000ull) | (u32)(~(u32)slot);
                cand_box[slot] = sbox[r];
            }
        }
    }
}

// Single block: exact global top-200 by 21-way merge of per-class sorted lists,
// then output + fallback path.
__global__ __launch_bounds__(256) void topk_kernel(
    const u64* __restrict__ cand_key,
    const float4* __restrict__ cand_box,
    const u64* __restrict__ fb_key,
    const float4* __restrict__ fb_box,
    float* __restrict__ out)   // [800 boxes][200 labels][200 scores]
{
    const int t = threadIdx.x;
    __shared__ u64 keys[LL * CAP];
    __shared__ u64 merged[CAP];

    for (int i = t; i < LL * CAP; i += 256) keys[i] = cand_key[i];
    __syncthreads();

    if (t < 64) {
        const int li = t;
        u64 cur = 0ull, nxt = 0ull;
        int pos = 0;
        if (li < LL) { cur = keys[li * CAP]; nxt = keys[li * CAP + 1]; }
        for (int o = 0; o < CAP; ++o) {
            u64 m = cur;
            for (int s = 1; s < 64; s <<= 1) {
                u64 o2 = shfl_xor_u64(m, s);
                if (o2 > m) m = o2;
            }
            if (m == 0ull) {
                if (t == 0) merged[o] = 0ull;
            } else if (cur == m) {   // unique keys -> single winner
                merged[o] = m;
                ++pos;
                cur = nxt;
                nxt = (pos + 1 < CAP) ? keys[li * CAP + pos + 1] : 0ull;
            }
        }
    }
    __syncthreads();

    for (int o = t; o < CAP; o += 256) {
        u64 key = merged[o];
        float4 b = make_float4(0.0f, 0.0f, 0.0f, 0.0f);
        float lab = 0.0f, sc = 0.0f;
        if (key != 0ull) {   // all real candidates have score > 0.5 -> valid
            u32 slot = ~(u32)(key & 0xFFFFFFFFull);
            sc = __uint_as_float((u32)(key >> 32));
            lab = (float)(slot / CAP);
            b = clip01(cand_box[slot]);
        }
        out[o * 4 + 0] = b.x;
        out[o * 4 + 1] = b.y;
        out[o * 4 + 2] = b.z;
        out[o * 4 + 3] = b.w;
        out[4 * CAP + o] = lab;
        out[5 * CAP + o] = sc;
    }
    __syncthreads();

    // fallback: no candidate with score>0.5 anywhere -> emit global best kept box at slot 0
    if (t == 0 && merged[0] == 0ull) {
        u64 best = 0ull;
        int bc = 0;
        for (int c = 0; c < LL; ++c) {
            u64 k = fb_key[c];
            if (k > best) { best = k; bc = c; }
        }
        float bs = __uint_as_float((u32)(best >> 32));
        if (bs >= 0.001f) {
            float4 bb = clip01(fb_box[bc]);
            out[0] = bb.x; out[1] = bb.y; out[2] = bb.z; out[3] = bb.w;
            out[4 * CAP] = (float)bc;
            out[5 * CAP] = bs;
        }
    }
}

extern "C" void kernel_launch(void* const* d_in, const int* in_sizes, int n_in,
                              void* d_out, int out_size, void* d_ws, size_t ws_size,
                              hipStream_t stream) {
    const float* roi    = (const float*)d_in[0];   // (1,2048,4)
    const float* deltas = (const float*)d_in[1];   // (1,2048,84)
    const float* probs  = (const float*)d_in[2];   // (1,2048,21)
    float* out = (float*)d_out;

    char* ws = (char*)d_ws;
    u64*    cand_key = (u64*)ws;                   // 4200*8  = 33600 B
    float4* cand_box = (float4*)(ws + 33600);      // 4200*16 = 67200 B (16B aligned)
    u64*    fb_key   = (u64*)(ws + 100800);        // 21*8    = 168 B
    float4* fb_box   = (float4*)(ws + 100976);     // 21*16   = 336 B (16B aligned)

    per_class_kernel<<<LL, 256, 0, stream>>>(roi, deltas, probs,
                                             cand_key, cand_box, fb_key, fb_box);
    topk_kernel<<<1, 256, 0, stream>>>(cand_key, cand_box, fb_key, fb_box, out);
}

// Round 2
// 163.479 us; speedup vs baseline: 4.7259x; 4.7259x over previous
//
#include <hip/hip_runtime.h>
#include <stdint.h>

#define NN 2048
#define LL 21
#define CAP 200
#define TOT (LL * CAP)

typedef unsigned long long u64;
typedef unsigned int u32;

__device__ __forceinline__ u64 shfl_u64(u64 v, int lane) {
    int lo = (int)(u32)(v & 0xFFFFFFFFull);
    int hi = (int)(u32)(v >> 32);
    lo = __shfl(lo, lane);
    hi = __shfl(hi, lane);
    return ((u64)(u32)hi << 32) | (u32)lo;
}

__device__ __forceinline__ float4 clip01(float4 b) {
    b.x = fminf(fmaxf(b.x, 0.0f), 1.0f);
    b.y = fminf(fmaxf(b.y, 0.0f), 1.0f);
    b.z = fminf(fmaxf(b.z, 0.0f), 1.0f);
    b.w = fminf(fmaxf(b.w, 0.0f), 1.0f);
    return b;
}

// decode with VARIANCES=(0.1,0.1,0.2,0.2); match np op order (no FMA contraction),
// exp via double for correct rounding to f32 (gave absmax 0.0 in R1).
__device__ __forceinline__ float4 decode_box(const float4 roi, const float4 dd) {
#pragma clang fp contract(off)
    float h  = roi.z - roi.x;
    float w  = roi.w - roi.y;
    float cy = roi.x + 0.5f * h;
    float cx = roi.y + 0.5f * w;
    float d0 = dd.x * 0.1f;
    float d1 = dd.y * 0.1f;
    float d2 = dd.z * 0.2f;
    float d3 = dd.w * 0.2f;
    float nh = (float)exp((double)d2) * h;
    float nw = (float)exp((double)d3) * w;
    float ncy = d0 * h + cy;
    float ncx = d1 * w + cx;
    return make_float4(ncy - 0.5f * nh, ncx - 0.5f * nw, ncy + 0.5f * nh, ncx + 0.5f * nw);
}

// exact replication of reference IoU>0.5 decision (division kept, op order kept)
__device__ __forceinline__ bool iou_gt(const float4 a, const float4 b) {
#pragma clang fp contract(off)
    float areaA = (a.z - a.x) * (a.w - a.y);
    float areaB = (b.z - b.x) * (b.w - b.y);
    float ih = fminf(a.z, b.z) - fmaxf(a.x, b.x);
    ih = fmaxf(ih, 0.0f);
    float iw = fminf(a.w, b.w) - fmaxf(a.y, b.y);
    iw = fmaxf(iw, 0.0f);
    float inter = ih * iw;
    float denom = ((areaA + areaB) - inter) + 1e-9f;
    return (inter / denom) > 0.5f;
}

// Kernel A: grid-parallel argmax + transposed key generation.
// keyT[cls][a] = score_bits<<32 | ~a  (descending-score, stable-anchor order)
__global__ __launch_bounds__(256) void score_kernel(
    const float* __restrict__ probs,   // (N, L)
    u64* __restrict__ keyT)            // (L, N)
{
    __shared__ float sp[256 * LL];
    const int a0 = blockIdx.x * 256;
    const int t = threadIdx.x;
    for (int i = t; i < 256 * LL; i += 256) sp[i] = probs[a0 * LL + i];
    __syncthreads();
    const float* row = sp + t * LL;   // stride 21 (odd) -> conflict-free
    float best = row[0];
    int bi = 0;
    for (int j = 1; j < LL; ++j) {
        float v = row[j];
        if (v > best) { best = v; bi = j; }
    }
    const u32 lowa = ~(u32)(a0 + t);
    for (int c = 0; c < LL; ++c) {
        float sc = (bi != 0) ? row[c] : 0.0f;
        keyT[c * NN + a0 + t] = ((u64)__float_as_uint(sc) << 32) | lowa;  // coalesced per c
    }
}

// Kernel B: one block per class. Compact keys>0.5 -> bitonic sort -> chunked exact
// greedy NMS with compacted kept-list + EARLY STOP at 200 kept -> emit candidates.
// Early stop is exact: boxes after the 200th kept can neither be emitted (cumsum cap)
// nor affect emitted boxes (suppression only flows into later ranks).
__global__ __launch_bounds__(256) void per_class_kernel(
    const u64* __restrict__ keyT,
    const float* __restrict__ roi,      // (N,4)
    const float* __restrict__ deltas,   // (N, L*4)
    u64* __restrict__ cand_key,         // (L*CAP)
    float4* __restrict__ cand_box,      // (L*CAP)
    u64* __restrict__ fb_key,           // (L)
    float4* __restrict__ fb_box)        // (L)
{
    const int cls = blockIdx.x;
    const int t = threadIdx.x;

    __shared__ u64 skey[NN];              // compacted + sorted qualifying keys
    __shared__ float4 kept[CAP];          // compacted kept boxes (suppressors)
    __shared__ float4 cbox[64];           // current chunk decoded boxes
    __shared__ u64 sup[4][64];            // intra-chunk partial suppression rows
    __shared__ unsigned char extq[4][64]; // external suppression flags per quarter
    __shared__ int sCnt;                  // compaction counter -> M
    __shared__ int sK;                    // kept count
    __shared__ unsigned long long gmax;   // block max key (fallback top-1)

    if (t == 0) { sCnt = 0; sK = 0; gmax = 0ull; }
    for (int s = t; s < CAP; s += 256) cand_key[cls * CAP + s] = 0ull;
    __syncthreads();

    // 1. load (coalesced), compact score>0.5, track max
    const u64 THRKEY = ((u64)0x3F000000u << 32) | 0xFFFFFFFFull;  // strict > 0.5
    u64 lq[NN / 256];
    int ln = 0;
    u64 lmax = 0ull;
    for (int i = t; i < NN; i += 256) {
        u64 k = keyT[cls * NN + i];
        if (k > lmax) lmax = k;
        if (k > THRKEY) lq[ln++] = k;
    }
    atomicMax(&gmax, lmax);
    int wbase = atomicAdd(&sCnt, ln);
    for (int j = 0; j < ln; ++j) skey[wbase + j] = lq[j];
    __syncthreads();

    const int M = sCnt;

    // 2. per-class fallback from block-max key (rank-0 box, always kept)
    if (t == 0) {
        u64 g = gmax;
        u32 a0 = ~(u32)(g & 0xFFFFFFFFull);
        float4 rb = *(const float4*)(roi + a0 * 4);
        float4 dd = *(const float4*)(deltas + a0 * (LL * 4) + cls * 4);
        fb_box[cls] = decode_box(rb, dd);
        fb_key[cls] = (g & 0xFFFFFFFF00000000ull) | (u32)(~(u32)(cls * NN));
    }

    // 3. bitonic sort (descending) over next-pow2 >= M, padded with 0
    int npow = 64;
    while (npow < M) npow <<= 1;
    for (int i = M + t; i < npow; i += 256) skey[i] = 0ull;
    __syncthreads();
    for (int k = 2; k <= npow; k <<= 1) {
        for (int j = k >> 1; j > 0; j >>= 1) {
            for (int i = t; i < npow; i += 256) {
                int ixj = i ^ j;
                if (ixj > i) {
                    u64 a = skey[i], b = skey[ixj];
                    bool dsc = ((i & k) == 0);
                    if (dsc ? (a < b) : (a > b)) { skey[i] = b; skey[ixj] = a; }
                }
            }
            __syncthreads();
        }
    }

    // 4. chunked greedy NMS with early stop
    const int q = t >> 6, r = t & 63;
    for (int base = 0; base < M; base += 64) {
        const int K = sK;
        if (K >= CAP) break;
        const int nb = min(64, M - base);

        // 4a. lazy decode of this chunk (wave 0)
        if (t < nb) {
            u32 a = ~(u32)(skey[base + t] & 0xFFFFFFFFull);
            float4 rb = *(const float4*)(roi + a * 4);
            float4 dd = *(const float4*)(deltas + a * (LL * 4) + cls * 4);
            cbox[t] = decode_box(rb, dd);
        }
        __syncthreads();

        // 4b. intra-chunk pair bits: thread (q,r) covers r2 in quarter q
        u64 bits = 0ull;
        if (r < nb) {
            float4 br = cbox[r];
            int lo = max(r + 1, q * 16), hi = min(nb, (q + 1) * 16);
            for (int r2 = lo; r2 < hi; ++r2)
                if (iou_gt(br, cbox[r2])) bits |= (1ull << r2);
        }
        sup[q][r] = bits;

        // 4c. external suppression vs compacted kept list (quartered)
        bool f = false;
        if (r < nb && K > 0) {
            float4 bm = cbox[r];
            int per = (K + 3) >> 2;
            int e0 = q * per, e1 = min(K, e0 + per);
            for (int e = e0; e < e1; ++e) {
                if (iou_gt(kept[e], bm)) { f = true; break; }
            }
        }
        extq[q][r] = f ? 1 : 0;
        __syncthreads();

        // 4d. wave-synchronous sequential resolve + emission (wave 0)
        if (t < 64) {
            u64 row = sup[0][t] | sup[1][t] | sup[2][t] | sup[3][t];
            bool ext = (t < nb) ? ((extq[0][t] | extq[1][t] | extq[2][t] | extq[3][t]) != 0)
                                : true;
            u64 removed = __ballot(ext);
            u64 keepb = 0ull;
            for (int rr = 0; rr < nb; ++rr) {
                u64 rowr = shfl_u64(row, rr);   // independent of serial chain -> pipelined
                if (!((removed >> rr) & 1ull)) {
                    keepb |= (1ull << rr);
                    removed |= rowr;
                }
            }
            if (t < nb && ((keepb >> t) & 1ull)) {
                int krank = K + __popcll(keepb & ((1ull << t) - 1ull));
                if (krank < CAP) {
                    kept[krank] = cbox[t];
                    int slot = cls * CAP + krank;
                    // low bits ~slot: slot order isomorphic to flat index order ->
                    // reproduces lax.top_k stable tie-break
                    cand_key[slot] = (skey[base + t] & 0xFFFFFFFF00000000ull) | (u32)(~(u32)slot);
                    cand_box[slot] = cbox[t];
                }
            }
            if (t == 0) sK = K + __popcll(keepb);
        }
        __syncthreads();
    }
}

// Kernel C: exact global top-200 via score-bucket histogram filter + 512-wide
// bitonic sort of survivors (all keys unique; scores in (0.5,1) -> buckets 0..127).
__global__ __launch_bounds__(256) void topk_kernel(
    const u64* __restrict__ cand_key,
    const float4* __restrict__ cand_box,
    const u64* __restrict__ fb_key,
    const float4* __restrict__ fb_box,
    float* __restrict__ out)   // [800 boxes][200 labels][200 scores]
{
    const int t = threadIdx.x;
    __shared__ u64 keys[TOT];
    __shared__ int hist[130];
    __shared__ int sBstar, sCnt2;
    __shared__ u64 keys2[512];

    for (int i = t; i < 130; i += 256) hist[i] = 0;
    if (t == 0) sCnt2 = 0;
    __syncthreads();

    for (int i = t; i < TOT; i += 256) {
        u64 k = cand_key[i];
        keys[i] = k;
        if (k != 0ull) {
            int b = (int)((u32)(k >> 48)) - 0x3F00;
            b = min(max(b, 0), 129);
            atomicAdd(&hist[b], 1);
        }
    }
    __syncthreads();

    if (t == 0) {
        int acc = 0, bs = 0;
        for (int b = 129; b >= 0; --b) {
            acc += hist[b];
            if (acc >= CAP) { bs = b; break; }
        }
        sBstar = bs;   // every key in bucket >= bs is selected; contains global top-200
    }
    __syncthreads();

    const int bstar = sBstar;
    for (int i = t; i < TOT; i += 256) {
        u64 k = keys[i];
        if (k != 0ull) {
            int b = (int)((u32)(k >> 48)) - 0x3F00;
            b = min(max(b, 0), 129);
            if (b >= bstar) {
                int p = atomicAdd(&sCnt2, 1);
                if (p < 512) keys2[p] = k;
            }
        }
    }
    __syncthreads();
    const int cnt = min(sCnt2, 512);
    for (int i = t; i < 512; i += 256)
        if (i >= cnt) keys2[i] = 0ull;
    __syncthreads();

    // bitonic sort 512, descending
    for (int k = 2; k <= 512; k <<= 1) {
        for (int j = k >> 1; j > 0; j >>= 1) {
            for (int i = t; i < 512; i += 256) {
                int ixj = i ^ j;
                if (ixj > i) {
                    u64 a = keys2[i], b = keys2[ixj];
                    bool dsc = ((i & k) == 0);
                    if (dsc ? (a < b) : (a > b)) { keys2[i] = b; keys2[ixj] = a; }
                }
            }
            __syncthreads();
        }
    }

    // emit top-200
    for (int o = t; o < CAP; o += 256) {
        u64 key = keys2[o];
        float4 b = make_float4(0.0f, 0.0f, 0.0f, 0.0f);
        float lab = 0.0f, sc = 0.0f;
        if (key != 0ull) {   // all real candidates have score > 0.5 -> valid
            u32 slot = ~(u32)(key & 0xFFFFFFFFull);
            sc = __uint_as_float((u32)(key >> 32));
            lab = (float)(slot / CAP);
            b = clip01(cand_box[slot]);
        }
        out[o * 4 + 0] = b.x;
        out[o * 4 + 1] = b.y;
        out[o * 4 + 2] = b.z;
        out[o * 4 + 3] = b.w;
        out[4 * CAP + o] = lab;
        out[5 * CAP + o] = sc;
    }
    __syncthreads();

    // fallback: no candidate anywhere -> global best kept box (rank-0 of best class)
    if (t == 0 && keys2[0] == 0ull) {
        u64 best = 0ull;
        int bc = 0;
        for (int c = 0; c < LL; ++c) {
            u64 k = fb_key[c];
            if (k > best) { best = k; bc = c; }
        }
        float bs = __uint_as_float((u32)(best >> 32));
        if (bs >= 0.001f) {
            float4 bb = clip01(fb_box[bc]);
            out[0] = bb.x; out[1] = bb.y; out[2] = bb.z; out[3] = bb.w;
            out[4 * CAP] = (float)bc;
            out[5 * CAP] = bs;
        }
    }
}

extern "C" void kernel_launch(void* const* d_in, const int* in_sizes, int n_in,
                              void* d_out, int out_size, void* d_ws, size_t ws_size,
                              hipStream_t stream) {
    const float* roi    = (const float*)d_in[0];   // (1,2048,4)
    const float* deltas = (const float*)d_in[1];   // (1,2048,84)
    const float* probs  = (const float*)d_in[2];   // (1,2048,21)
    float* out = (float*)d_out;

    char* ws = (char*)d_ws;
    u64*    keyT     = (u64*)ws;                    // 21*2048*8 = 344064 B
    u64*    cand_key = (u64*)(ws + 344064);         // 4200*8   = 33600 B
    float4* cand_box = (float4*)(ws + 377664);      // 4200*16  = 67200 B (16B aligned)
    u64*    fb_key   = (u64*)(ws + 444864);         // 21*8     = 168 B
    float4* fb_box   = (float4*)(ws + 445040);      // 21*16    = 336 B (16B aligned)

    score_kernel<<<NN / 256, 256, 0, stream>>>(probs, keyT);
    per_class_kernel<<<LL, 256, 0, stream>>>(keyT, roi, deltas,
                                             cand_key, cand_box, fb_key, fb_box);
    topk_kernel<<<1, 256, 0, stream>>>(cand_key, cand_box, fb_key, fb_box, out);
}